// Round 9
// baseline (118.421 us; speedup 1.0000x reference)
//
#include <hip/hip_runtime.h>

// FeatureAttentionLayer: B=32, W=128, K=128, E=256, fp32.
//   L[i][e] = sum_w x[b][w][i]*lin_w[e][w] + lin_b[e]
//   R[j][e] = sum_w x[b][w][j]*lin_w[e][128+w]
//   e[i][j] = 0.6(dL[i]+dR[j]) + sum_e 0.4a[e]|L+R| + bias   (LReLU identity)
//   att = softmax_j; out[b][w][i] = sigmoid(sum_j att[i][j]*x[b][w][j])
//
// ws: P[b][r][k] (r<256: L^T rows; r>=256: R^T rows), 2M floats; a6/a4 @ 2M.
// Round-9: three different in-loop-load K1s all measured ~30us; round-3's
// ping-pong-prefetch global-only K1 measured 14.6us at 1 wave/SIMD. Revert to
// that structure + 2x TLP (512 blocks, 4k x 4r per thread) + 128-FMA chunks
// so the depth-2 prefetch covers ~L2 latency. No launch_bounds cap (r5: cap
// + unroll => spill). w-loads are 16-lane broadcast (4 distinct addrs/instr),
// x-loads 256B contiguous. K2 unchanged (~6us, near its VALU floor).

typedef float v2f __attribute__((ext_vector_type(2)));
typedef float v4f __attribute__((ext_vector_type(4)));

#define WS_A6  2097152
#define WS_A4  (2097152 + 256)

// ---------------- K1: projection GEMM, ping-pong register prefetch ----------------
// grid (32 b, 2 kt, 8 rt), 256 thr; thread: 4 k (kp) x 4 r (ep).
__global__ void k_linear(
    const float* __restrict__ x, const float* __restrict__ lin_w,
    const float* __restrict__ lin_b, const float* __restrict__ a,
    float* __restrict__ ws)
{
    const int t = threadIdx.x;
    const int b = blockIdx.x, kt = blockIdx.y, rt = blockIdx.z;

    if (b == 0 && kt == 0 && rt == 0) {   // fold a once (K2 is stream-ordered after)
        float av = a[t];
        ws[WS_A6 + t] = 0.6f * av;
        ws[WS_A4 + t] = 0.4f * av;
    }

    const int kp = t & 15, ep = t >> 4;
    const int k0 = kt * 64 + kp * 4;      // 4 consecutive k
    const int r0 = rt * 64 + ep * 4;      // 4 consecutive r
    const bool isL = (rt < 4);

    const float* xg = x + b * 16384 + k0;                 // + w*128 per row
    const float* Ab = isL ? (lin_w + (size_t)r0 * 256)
                          : (lin_w + (size_t)(r0 - 256) * 256 + 128);

    float acc[4][4] = {};                 // [ee][kk]
    v4f xA[8], wA[8], xB[8], wB[8];       // chunk = 8 w-steps; ping-pong

#define K1LD(X, W, c) do {                                              \
    _Pragma("unroll") for (int ww = 0; ww < 8; ++ww)                    \
      X[ww] = *(const v4f*)(xg + ((c) * 8 + ww) * 128);                 \
    _Pragma("unroll") for (int ee = 0; ee < 4; ++ee)                    \
      _Pragma("unroll") for (int h = 0; h < 2; ++h)                     \
        W[ee * 2 + h] = *(const v4f*)(Ab + ee * 256 + (c) * 8 + h * 4); \
    } while (0)

#define K1CP(X, W) do {                                                 \
    _Pragma("unroll") for (int ww = 0; ww < 8; ++ww)                    \
      _Pragma("unroll") for (int ee = 0; ee < 4; ++ee) {                \
        const float w_ = W[ee * 2 + (ww >> 2)][ww & 3];                 \
        _Pragma("unroll") for (int kk = 0; kk < 4; ++kk)                \
          acc[ee][kk] = fmaf(X[ww][kk], w_, acc[ee][kk]); } } while (0)

    K1LD(xA, wA, 0);
    #pragma unroll 1
    for (int c = 0; c < 16; c += 2) {
        K1LD(xB, wB, c + 1);
        K1CP(xA, wA);
        if (c + 2 < 16) K1LD(xA, wA, c + 2);
        K1CP(xB, wB);
    }

    #pragma unroll
    for (int ee = 0; ee < 4; ++ee) {
        const float lb = isL ? lin_b[r0 + ee] : 0.f;
        float* dst = ws + ((size_t)(b * 512 + r0 + ee) * 128 + k0);
        *(v4f*)dst = (v4f){acc[ee][0] + lb, acc[ee][1] + lb,
                           acc[ee][2] + lb, acc[ee][3] + lb};
    }
}

// ---------------- K2: logits + softmax + PV + sigmoid (unchanged) ----------------
// grid (32 b, 8 it of 16 i-rows), 256 thr.
// R staged in LDS (4 chunks of 64 e-rows, double-buffered via 8 v4f regs);
// e-loop all-LDS. Phase-2 x transposed into the dead R buffers (XOR swizzle).
__global__ __launch_bounds__(256, 1) void k_attn(
    const float* __restrict__ x, const float* __restrict__ bias,
    const float* __restrict__ ws, float* __restrict__ out)
{
    __shared__ float Rs[2][8192];      // 64 KB; reused as xT after e-loop
    __shared__ float Lt[256 * 16];     // 16 KB: Lt[e*16+il]
    __shared__ float att[16 * 132];    // 8.4 KB
    __shared__ float as6[256], as4[256];

    const int t = threadIdx.x;
    const int b = blockIdx.x, it = blockIdx.y;
    const float* Pb = ws + (size_t)b * 65536;
    const float* Rsrc = Pb + 32768;    // R^T rows, contiguous 32 KB per chunk

    v4f rx[8];
#define RLOAD(n_) do { const float* s_ = Rsrc + (n_) * 8192 + t * 4;  \
    _Pragma("unroll") for (int q = 0; q < 8; ++q)                     \
      rx[q] = *(const v4f*)(s_ + q * 1024); } while (0)

    RLOAD(0);

    // stage L^T tile (coalesced) + a-vectors
    {
        const float* Ls = Pb + it * 16;
        #pragma unroll
        for (int q = 0; q < 4; ++q) {
            const int idx = t + q * 256;
            const int e = idx >> 2, il4 = (idx & 3) * 4;
            *(v4f*)&Lt[e * 16 + il4] = *(const v4f*)(Ls + e * 128 + il4);
        }
    }
    as6[t] = ws[WS_A6 + t];
    as4[t] = ws[WS_A4 + t];

    const int jp = t & 31, iq = t >> 5;
    const int j0 = jp * 4, il0 = iq * 2;

    float acc0[4] = {}, acc1[4] = {};      // sum 0.4a*|L+R| per jj, rows il0/il0+1
    float dr[4] = {};                      // sum 0.6a*R per jj
    float dl0 = 0.f, dl1 = 0.f;            // sum 0.6a*L per row

    #pragma unroll 1
    for (int n = 0; n < 4; ++n) {
        float* rs = &Rs[n & 1][0];
        {   // commit staged chunk n to LDS (linear, conflict-free sweep)
            float* d_ = rs + t * 4;
            #pragma unroll
            for (int q = 0; q < 8; ++q) *(v4f*)(d_ + q * 1024) = rx[q];
        }
        if (n < 3) RLOAD(n + 1);           // global latency covered by compute below
        __syncthreads();

        const int eg0 = n * 64;
        #pragma unroll
        for (int g = 0; g < 16; ++g) {
            const int e0 = g * 4, eg = eg0 + e0;
            v4f rv[4]; float2 lv[4];
            #pragma unroll
            for (int u = 0; u < 4; ++u) {
                rv[u] = *(const v4f*)&rs[(e0 + u) * 128 + j0];
                lv[u] = *(const float2*)&Lt[(eg + u) * 16 + il0];
            }
            const v4f a6v = *(const v4f*)&as6[eg];
            const v4f a4v = *(const v4f*)&as4[eg];
            #pragma unroll
            for (int u = 0; u < 4; ++u) {
                const float a6u = a6v[u], a4u = a4v[u];
                const float l0 = lv[u].x, l1 = lv[u].y;
                dl0 = fmaf(a6u, l0, dl0);
                dl1 = fmaf(a6u, l1, dl1);
                #pragma unroll
                for (int jj = 0; jj < 4; ++jj) {
                    const float r = rv[u][jj];
                    dr[jj]   = fmaf(a6u, r, dr[jj]);
                    acc0[jj] = fmaf(a4u, fabsf(l0 + r), acc0[jj]);
                    acc1[jj] = fmaf(a4u, fabsf(l1 + r), acc1[jj]);
                }
            }
        }
    }
    __syncthreads();                       // all waves done with Rs -> reuse as xT

    // stage xT[j][w ^ swz(j)] into the dead R buffers (64 KB exactly).
    // swz = ((j>>2)&15)<<1 : write ~2-way (free), read conflict-free, keeps
    // 8B alignment for the v2f reads.
    float* xT = &Rs[0][0];
    {
        const float* xg = x + b * 16384;
        #pragma unroll
        for (int q = 0; q < 16; ++q) {
            const int idx = t + q * 256;
            const int w = idx >> 5, j4 = (idx & 31) * 4;
            const int s = ((j4 >> 2) & 15) << 1;
            const v4f xv = *(const v4f*)(xg + w * 128 + j4);
            xT[(j4 + 0) * 128 + (w ^ s)] = xv[0];
            xT[(j4 + 1) * 128 + (w ^ s)] = xv[1];
            xT[(j4 + 2) * 128 + (w ^ s)] = xv[2];
            xT[(j4 + 3) * 128 + (w ^ s)] = xv[3];
        }
    }

    // softmax over j (row lives in one 32-lane half-wave)
    const int i0r = it * 16 + il0;
    float ev0[4], ev1[4];
    {
        const v4f b0 = *(const v4f*)(bias + (i0r + 0) * 128 + j0);
        const v4f b1 = *(const v4f*)(bias + (i0r + 1) * 128 + j0);
        #pragma unroll
        for (int jj = 0; jj < 4; ++jj) {
            ev0[jj] = acc0[jj] + dl0 + dr[jj] + b0[jj];
            ev1[jj] = acc1[jj] + dl1 + dr[jj] + b1[jj];
        }
    }
#define SOFTMAX_ROW(EV, ROW) do {                                               \
    float m_ = fmaxf(fmaxf(EV[0], EV[1]), fmaxf(EV[2], EV[3]));                 \
    _Pragma("unroll") for (int d_ = 1; d_ <= 16; d_ <<= 1)                      \
        m_ = fmaxf(m_, __shfl_xor(m_, d_));                                     \
    float p0 = __expf(EV[0] - m_), p1 = __expf(EV[1] - m_);                     \
    float p2 = __expf(EV[2] - m_), p3 = __expf(EV[3] - m_);                     \
    float s_ = p0 + p1 + p2 + p3;                                               \
    _Pragma("unroll") for (int d_ = 1; d_ <= 16; d_ <<= 1)                      \
        s_ += __shfl_xor(s_, d_);                                               \
    const float inv_ = 1.f / s_;                                                \
    *(v4f*)&att[(ROW) * 132 + j0] =                                             \
        (v4f){p0 * inv_, p1 * inv_, p2 * inv_, p3 * inv_}; } while (0)

    SOFTMAX_ROW(ev0, il0 + 0);
    SOFTMAX_ROW(ev1, il0 + 1);
    __syncthreads();

    // phase 2: out[b][w][i] = sigmoid(sum_j att[i][j]*x[b][w][j]); lane 2w x 4i
    const int iq2 = t & 3, wp = t >> 2;
    const int i4 = iq2 * 4, w0 = wp * 2;
    float o[2][4] = {};
    #pragma unroll 4
    for (int jc = 0; jc < 32; ++jc) {
        const int wx = w0 ^ ((jc & 15) << 1);
        v4f av[4]; v2f xv[4];
        #pragma unroll
        for (int q = 0; q < 4; ++q)
            av[q] = *(const v4f*)&att[(i4 + q) * 132 + jc * 4];
        #pragma unroll
        for (int u = 0; u < 4; ++u)
            xv[u] = *(const v2f*)&xT[(jc * 4 + u) * 128 + wx];
        #pragma unroll
        for (int u = 0; u < 4; ++u)
            #pragma unroll
            for (int q = 0; q < 4; ++q) {
                o[0][q] = fmaf(xv[u].x, av[q][u], o[0][q]);
                o[1][q] = fmaf(xv[u].y, av[q][u], o[1][q]);
            }
    }
    #pragma unroll
    for (int w = 0; w < 2; ++w) {
        v4f r;
        r[0] = 1.f / (1.f + __expf(-o[w][0]));
        r[1] = 1.f / (1.f + __expf(-o[w][1]));
        r[2] = 1.f / (1.f + __expf(-o[w][2]));
        r[3] = 1.f / (1.f + __expf(-o[w][3]));
        *(v4f*)(out + (size_t)b * 16384 + (w0 + w) * 128 + it * 16 + i4) = r;
    }
}

extern "C" void kernel_launch(void* const* d_in, const int* in_sizes, int n_in,
                              void* d_out, int out_size, void* d_ws, size_t ws_size,
                              hipStream_t stream) {
    const float* x     = (const float*)d_in[0];
    const float* lin_w = (const float*)d_in[1];
    const float* lin_b = (const float*)d_in[2];
    const float* a     = (const float*)d_in[3];
    const float* bias  = (const float*)d_in[4];
    float* ws  = (float*)d_ws;
    float* out = (float*)d_out;

    k_linear<<<dim3(32, 2, 8), 256, 0, stream>>>(x, lin_w, lin_b, a, ws);
    k_attn  <<<dim3(32, 8), 256, 0, stream>>>(x, bias, ws, out);
}

// Round 10
// 40.978 us; speedup vs baseline: 2.8898x; 2.8898x over previous
//
#include <hip/hip_runtime.h>

// FeatureAttentionLayer: B=32, W=128, K=128, E=256, fp32.
//   L[i][e] = sum_w x[b][w][i]*lin_w[e][w] + lin_b[e]
//   R[j][e] = sum_w x[b][w][j]*lin_w[e][128+w]
//   e[i][j] = 0.6(dL[i]+dR[j]) + sum_e 0.4a[e]|L+R| + bias   (LReLU identity)
//   att = softmax_j; out[b][w][i] = sigmoid(sum_j att[i][j]*x[b][w][j])
//
// ws: P[b][r][k] (r<256: L^T rows; r>=256: R^T rows), 2M floats; a6/a4 @ 2M.
// Round-10: measured K1 table: R3 compiler-scheduled global ping-pong =
// 14.6us; LDS variants ~30us; deep reg rings 112-290us (collapsed/spilled).
// So: round-3 k_linear VERBATIM (loads/schedule/grid), only the store block
// rewritten to the P[b][r][k] layout the 6us K2 consumes. K2 unchanged.

typedef float v2f __attribute__((ext_vector_type(2)));
typedef float v4f __attribute__((ext_vector_type(4)));

#define WS_A6  2097152
#define WS_A4  (2097152 + 256)

// ---------------- K1: projection GEMM (round-3 structure) ----------------
// grid (32 b, 8 rt), 256 thr; thread: 8 k (kp) x 4 r (ep); ping-pong depth 2,
// compiler-scheduled. x loads: 2x16B per w-row covering the full 512B row;
// w loads: 16-lane broadcast (4 distinct addrs/instr).
__global__ __launch_bounds__(256) void k_linear(
    const float* __restrict__ x, const float* __restrict__ lin_w,
    const float* __restrict__ lin_b, const float* __restrict__ a,
    float* __restrict__ ws)
{
    const int t = threadIdx.x;
    const int b = blockIdx.x, rt = blockIdx.y;

    if (b == 0 && rt == 0) {              // fold a once (K2 is stream-ordered after)
        float av = a[t];
        ws[WS_A6 + t] = 0.6f * av;
        ws[WS_A4 + t] = 0.4f * av;
    }

    const int kp = t & 15, ep = t >> 4;
    const int k0 = kp * 8;                // 8 consecutive k
    const int r0 = rt * 64 + ep * 4;      // 4 consecutive r
    const bool isL = (rt < 4);

    const float* xb = x + b * 16384 + k0;
    const float* Ab = isL ? (lin_w + (size_t)r0 * 256)
                          : (lin_w + (size_t)(r0 - 256) * 256 + 128);

    float acc[4][8];                      // [ee][kk]
    #pragma unroll
    for (int ee = 0; ee < 4; ++ee)
        #pragma unroll
        for (int kk = 0; kk < 8; ++kk) acc[ee][kk] = 0.f;

    v4f x0A[4], x1A[4], wA[4], x0B[4], x1B[4], wB[4];

#define K1LD(X0, X1, WV, wc) do { const int w4 = (wc) * 4;                 \
    _Pragma("unroll") for (int ww = 0; ww < 4; ++ww) {                     \
      X0[ww] = *(const v4f*)(xb + (w4 + ww) * 128);                        \
      X1[ww] = *(const v4f*)(xb + (w4 + ww) * 128 + 4); }                  \
    _Pragma("unroll") for (int ee = 0; ee < 4; ++ee)                       \
      WV[ee] = *(const v4f*)(Ab + ee * 256 + w4); } while (0)

#define K1CP(X0, X1, WV) do {                                              \
    _Pragma("unroll") for (int ww = 0; ww < 4; ++ww)                       \
      _Pragma("unroll") for (int ee = 0; ee < 4; ++ee) {                   \
        const float wv = WV[ee][ww];                                       \
        _Pragma("unroll") for (int kk = 0; kk < 4; ++kk) {                 \
          acc[ee][kk]     = fmaf(X0[ww][kk], wv, acc[ee][kk]);             \
          acc[ee][kk + 4] = fmaf(X1[ww][kk], wv, acc[ee][kk + 4]); } } } while (0)

    K1LD(x0A, x1A, wA, 0);
    for (int wc = 0; wc < 32; wc += 2) {
        K1LD(x0B, x1B, wB, wc + 1);
        K1CP(x0A, x1A, wA);
        K1LD(x0A, x1A, wA, (wc + 2) & 31);   // wraps to 0 on last iter (harmless)
        K1CP(x0B, x1B, wB);
    }

    // store to P[b][r][k] (k-contiguous rows; 16 lanes x 32B = coalesced 512B)
    #pragma unroll
    for (int ee = 0; ee < 4; ++ee) {
        const float lb = isL ? lin_b[r0 + ee] : 0.f;
        float* dst = ws + ((size_t)(b * 512 + r0 + ee) * 128 + k0);
        *(v4f*)dst       = (v4f){acc[ee][0] + lb, acc[ee][1] + lb,
                                 acc[ee][2] + lb, acc[ee][3] + lb};
        *(v4f*)(dst + 4) = (v4f){acc[ee][4] + lb, acc[ee][5] + lb,
                                 acc[ee][6] + lb, acc[ee][7] + lb};
    }
}

// ---------------- K2: logits + softmax + PV + sigmoid (unchanged) ----------------
// grid (32 b, 8 it of 16 i-rows), 256 thr.
// R staged in LDS (4 chunks of 64 e-rows, double-buffered via 8 v4f regs);
// e-loop all-LDS. Phase-2 x transposed into the dead R buffers (XOR swizzle).
__global__ __launch_bounds__(256, 1) void k_attn(
    const float* __restrict__ x, const float* __restrict__ bias,
    const float* __restrict__ ws, float* __restrict__ out)
{
    __shared__ float Rs[2][8192];      // 64 KB; reused as xT after e-loop
    __shared__ float Lt[256 * 16];     // 16 KB: Lt[e*16+il]
    __shared__ float att[16 * 132];    // 8.4 KB
    __shared__ float as6[256], as4[256];

    const int t = threadIdx.x;
    const int b = blockIdx.x, it = blockIdx.y;
    const float* Pb = ws + (size_t)b * 65536;
    const float* Rsrc = Pb + 32768;    // R^T rows, contiguous 32 KB per chunk

    v4f rx[8];
#define RLOAD(n_) do { const float* s_ = Rsrc + (n_) * 8192 + t * 4;  \
    _Pragma("unroll") for (int q = 0; q < 8; ++q)                     \
      rx[q] = *(const v4f*)(s_ + q * 1024); } while (0)

    RLOAD(0);

    // stage L^T tile (coalesced) + a-vectors
    {
        const float* Ls = Pb + it * 16;
        #pragma unroll
        for (int q = 0; q < 4; ++q) {
            const int idx = t + q * 256;
            const int e = idx >> 2, il4 = (idx & 3) * 4;
            *(v4f*)&Lt[e * 16 + il4] = *(const v4f*)(Ls + e * 128 + il4);
        }
    }
    as6[t] = ws[WS_A6 + t];
    as4[t] = ws[WS_A4 + t];

    const int jp = t & 31, iq = t >> 5;
    const int j0 = jp * 4, il0 = iq * 2;

    float acc0[4] = {}, acc1[4] = {};      // sum 0.4a*|L+R| per jj, rows il0/il0+1
    float dr[4] = {};                      // sum 0.6a*R per jj
    float dl0 = 0.f, dl1 = 0.f;            // sum 0.6a*L per row

    #pragma unroll 1
    for (int n = 0; n < 4; ++n) {
        float* rs = &Rs[n & 1][0];
        {   // commit staged chunk n to LDS (linear, conflict-free sweep)
            float* d_ = rs + t * 4;
            #pragma unroll
            for (int q = 0; q < 8; ++q) *(v4f*)(d_ + q * 1024) = rx[q];
        }
        if (n < 3) RLOAD(n + 1);           // global latency covered by compute below
        __syncthreads();

        const int eg0 = n * 64;
        #pragma unroll
        for (int g = 0; g < 16; ++g) {
            const int e0 = g * 4, eg = eg0 + e0;
            v4f rv[4]; float2 lv[4];
            #pragma unroll
            for (int u = 0; u < 4; ++u) {
                rv[u] = *(const v4f*)&rs[(e0 + u) * 128 + j0];
                lv[u] = *(const float2*)&Lt[(eg + u) * 16 + il0];
            }
            const v4f a6v = *(const v4f*)&as6[eg];
            const v4f a4v = *(const v4f*)&as4[eg];
            #pragma unroll
            for (int u = 0; u < 4; ++u) {
                const float a6u = a6v[u], a4u = a4v[u];
                const float l0 = lv[u].x, l1 = lv[u].y;
                dl0 = fmaf(a6u, l0, dl0);
                dl1 = fmaf(a6u, l1, dl1);
                #pragma unroll
                for (int jj = 0; jj < 4; ++jj) {
                    const float r = rv[u][jj];
                    dr[jj]   = fmaf(a6u, r, dr[jj]);
                    acc0[jj] = fmaf(a4u, fabsf(l0 + r), acc0[jj]);
                    acc1[jj] = fmaf(a4u, fabsf(l1 + r), acc1[jj]);
                }
            }
        }
    }
    __syncthreads();                       // all waves done with Rs -> reuse as xT

    // stage xT[j][w ^ swz(j)] into the dead R buffers (64 KB exactly).
    // swz = ((j>>2)&15)<<1 : write ~2-way (free), read conflict-free, keeps
    // 8B alignment for the v2f reads.
    float* xT = &Rs[0][0];
    {
        const float* xg = x + b * 16384;
        #pragma unroll
        for (int q = 0; q < 16; ++q) {
            const int idx = t + q * 256;
            const int w = idx >> 5, j4 = (idx & 31) * 4;
            const int s = ((j4 >> 2) & 15) << 1;
            const v4f xv = *(const v4f*)(xg + w * 128 + j4);
            xT[(j4 + 0) * 128 + (w ^ s)] = xv[0];
            xT[(j4 + 1) * 128 + (w ^ s)] = xv[1];
            xT[(j4 + 2) * 128 + (w ^ s)] = xv[2];
            xT[(j4 + 3) * 128 + (w ^ s)] = xv[3];
        }
    }

    // softmax over j (row lives in one 32-lane half-wave)
    const int i0r = it * 16 + il0;
    float ev0[4], ev1[4];
    {
        const v4f b0 = *(const v4f*)(bias + (i0r + 0) * 128 + j0);
        const v4f b1 = *(const v4f*)(bias + (i0r + 1) * 128 + j0);
        #pragma unroll
        for (int jj = 0; jj < 4; ++jj) {
            ev0[jj] = acc0[jj] + dl0 + dr[jj] + b0[jj];
            ev1[jj] = acc1[jj] + dl1 + dr[jj] + b1[jj];
        }
    }
#define SOFTMAX_ROW(EV, ROW) do {                                               \
    float m_ = fmaxf(fmaxf(EV[0], EV[1]), fmaxf(EV[2], EV[3]));                 \
    _Pragma("unroll") for (int d_ = 1; d_ <= 16; d_ <<= 1)                      \
        m_ = fmaxf(m_, __shfl_xor(m_, d_));                                     \
    float p0 = __expf(EV[0] - m_), p1 = __expf(EV[1] - m_);                     \
    float p2 = __expf(EV[2] - m_), p3 = __expf(EV[3] - m_);                     \
    float s_ = p0 + p1 + p2 + p3;                                               \
    _Pragma("unroll") for (int d_ = 1; d_ <= 16; d_ <<= 1)                      \
        s_ += __shfl_xor(s_, d_);                                               \
    const float inv_ = 1.f / s_;                                                \
    *(v4f*)&att[(ROW) * 132 + j0] =                                             \
        (v4f){p0 * inv_, p1 * inv_, p2 * inv_, p3 * inv_}; } while (0)

    SOFTMAX_ROW(ev0, il0 + 0);
    SOFTMAX_ROW(ev1, il0 + 1);
    __syncthreads();

    // phase 2: out[b][w][i] = sigmoid(sum_j att[i][j]*x[b][w][j]); lane 2w x 4i
    const int iq2 = t & 3, wp = t >> 2;
    const int i4 = iq2 * 4, w0 = wp * 2;
    float o[2][4] = {};
    #pragma unroll 4
    for (int jc = 0; jc < 32; ++jc) {
        const int wx = w0 ^ ((jc & 15) << 1);
        v4f av[4]; v2f xv[4];
        #pragma unroll
        for (int q = 0; q < 4; ++q)
            av[q] = *(const v4f*)&att[(i4 + q) * 132 + jc * 4];
        #pragma unroll
        for (int u = 0; u < 4; ++u)
            xv[u] = *(const v2f*)&xT[(jc * 4 + u) * 128 + wx];
        #pragma unroll
        for (int u = 0; u < 4; ++u)
            #pragma unroll
            for (int q = 0; q < 4; ++q) {
                o[0][q] = fmaf(xv[u].x, av[q][u], o[0][q]);
                o[1][q] = fmaf(xv[u].y, av[q][u], o[1][q]);
            }
    }
    #pragma unroll
    for (int w = 0; w < 2; ++w) {
        v4f r;
        r[0] = 1.f / (1.f + __expf(-o[w][0]));
        r[1] = 1.f / (1.f + __expf(-o[w][1]));
        r[2] = 1.f / (1.f + __expf(-o[w][2]));
        r[3] = 1.f / (1.f + __expf(-o[w][3]));
        *(v4f*)(out + (size_t)b * 16384 + (w0 + w) * 128 + it * 16 + i4) = r;
    }
}

extern "C" void kernel_launch(void* const* d_in, const int* in_sizes, int n_in,
                              void* d_out, int out_size, void* d_ws, size_t ws_size,
                              hipStream_t stream) {
    const float* x     = (const float*)d_in[0];
    const float* lin_w = (const float*)d_in[1];
    const float* lin_b = (const float*)d_in[2];
    const float* a     = (const float*)d_in[3];
    const float* bias  = (const float*)d_in[4];
    float* ws  = (float*)d_ws;
    float* out = (float*)d_out;

    k_linear<<<dim3(32, 8), 256, 0, stream>>>(x, lin_w, lin_b, a, ws);
    k_attn  <<<dim3(32, 8), 256, 0, stream>>>(x, bias, ws, out);
}

// Round 11
// 33.682 us; speedup vs baseline: 3.5159x; 1.2166x over previous
//
#include <hip/hip_runtime.h>

// FeatureAttentionLayer: B=32, W=128, K=128, E=256, fp32.
//   L[i][e] = sum_w x[b][w][i]*lin_w[e][w] + lin_b[e]
//   R[j][e] = sum_w x[b][w][j]*lin_w[e][128+w]
//   e[i][j] = 0.6(dL[i]+dR[j]) + sum_e 0.4a[e]|L+R| + bias   (LReLU identity)
//   att = softmax_j; out[b][w][i] = sigmoid(sum_j att[i][j]*x[b][w][j])
//
// ws: P[b][r][k] (r<256: L^T rows; r>=256: R^T rows), 2M floats; a6/a4 @ 2M.
// Round-11: five scalar K1 variants all ~30us (vs 3.4us VALU floor) — switch
// regime: K1 as bf16 MFMA GEMM (16x16x32). Error budget: bf16 RNE on x,lin_w
// -> |dL|~1.6e-3 -> out err ~2e-3 << 1.26e-2 threshold. Fragments are single
// aligned ds_read_b128; xT group-swizzled (g ^= (k>>3)&15) so transpose
// writes are <=4-way while frag reads stay uniform. K2 unchanged (~6us).

typedef float v2f __attribute__((ext_vector_type(2)));
typedef float v4f __attribute__((ext_vector_type(4)));
typedef short bf16x8 __attribute__((ext_vector_type(8)));

#define WS_A6  2097152
#define WS_A4  (2097152 + 256)

__device__ __forceinline__ unsigned pack_bf16x2(float a, float b) {
    unsigned ua = __builtin_bit_cast(unsigned, a);
    unsigned ub = __builtin_bit_cast(unsigned, b);
    ua = (ua + 0x7FFFu + ((ua >> 16) & 1u)) >> 16;   // RNE f32->bf16
    ub = (ub + 0x7FFFu + ((ub >> 16) & 1u)) >> 16;
    return ua | (ub << 16);
}

// ---------------- K1: projection GEMM via bf16 MFMA ----------------
// grid (32 b, 8 rt), 256 thr (4 waves). Block: 64 r x 128 k output tile.
// Wave: 16 r x 128 k = 8 mfma accs; K-dim = 128 w = 4 chunks of 32.
__global__ __launch_bounds__(256) void k_linear(
    const float* __restrict__ x, const float* __restrict__ lin_w,
    const float* __restrict__ lin_b, const float* __restrict__ a,
    float* __restrict__ ws)
{
    __shared__ unsigned short xT[128 * 136];  // xT[k][w'] bf16, swizzled (34 KB)
    __shared__ unsigned short As[64 * 136];   // As[rr][w]  bf16, linear   (17 KB)

    const int t = threadIdx.x;
    const int b = blockIdx.x, rt = blockIdx.y;
    const bool isL = (rt < 4);

    if (b == 0 && rt == 0) {                  // fold a once (K2 stream-ordered after)
        float av = a[t];
        ws[WS_A6 + t] = 0.6f * av;
        ws[WS_A4 + t] = 0.4f * av;
    }

    // ---- stage xT[k][w] = bf16(x[b][w][k]), col-group swizzle g^=(k>>3)&15 ----
    {
        const float* xg = x + b * 16384;
        #pragma unroll
        for (int q = 0; q < 8; ++q) {
            const int idx = t + q * 256;                 // 0..2047
            const int wp = idx >> 5;                     // w-pair 0..63
            const int k4 = (idx & 31) << 2;
            const v4f r0 = *(const v4f*)(xg + (2 * wp) * 128 + k4);
            const v4f r1 = *(const v4f*)(xg + (2 * wp + 1) * 128 + k4);
            const int g   = wp >> 2;                     // col group (8 elems)
            const int off = (2 * wp) & 7;
            #pragma unroll
            for (int u = 0; u < 4; ++u) {
                const int k = k4 + u;
                const int gs = g ^ ((k >> 3) & 15);
                *(unsigned*)&xT[k * 136 + (gs << 3) + off] = pack_bf16x2(r0[u], r1[u]);
            }
        }
    }
    // ---- stage As[rr][w] = bf16(A[rt*64+rr][w]) (linear; writes/reads uniform) ----
    {
        #pragma unroll
        for (int q = 0; q < 16; ++q) {
            const int idx = t + q * 256;                 // 0..4095
            const int rr = idx >> 6, wp2 = idx & 63;
            const int r = rt * 64 + rr;
            const float* Ag = isL ? (lin_w + (size_t)r * 256)
                                  : (lin_w + (size_t)(r - 256) * 256 + 128);
            const v2f wv = *(const v2f*)(Ag + 2 * wp2);
            *(unsigned*)&As[rr * 136 + 2 * wp2] = pack_bf16x2(wv.x, wv.y);
        }
    }
    __syncthreads();

    // ---- MFMA: D[m=r][n=k] = sum_w A[m][w] * B[w][n],  B[w][n] = xT[n][w] ----
    const int l = t & 63, wave = t >> 6;
    const int m0 = wave * 16;
    const int lr = l & 15, lg = l >> 4;

    bf16x8 af[4];
    #pragma unroll
    for (int kc = 0; kc < 4; ++kc)
        af[kc] = *(const bf16x8*)&As[(m0 + lr) * 136 + kc * 32 + lg * 8];

    v4f acc[8];
    #pragma unroll
    for (int nf = 0; nf < 8; ++nf) acc[nf] = (v4f){0.f, 0.f, 0.f, 0.f};

    #pragma unroll
    for (int nf = 0; nf < 8; ++nf) {
        const int row = nf * 16 + lr;                    // k-output row of xT
        const int vr = (row >> 3) & 15;
        #pragma unroll
        for (int kc = 0; kc < 4; ++kc) {
            const int g = kc * 4 + lg;
            const bf16x8 bfv = *(const bf16x8*)&xT[row * 136 + ((g ^ vr) << 3)];
            acc[nf] = __builtin_amdgcn_mfma_f32_16x16x32_bf16(af[kc], bfv, acc[nf], 0, 0, 0);
        }
    }

    // ---- store P[b][r][k]: r = rt*64 + m0 + lg*4 + j, k = nf*16 + lr ----
    const int rb = rt * 64 + m0 + lg * 4;
    #pragma unroll
    for (int j = 0; j < 4; ++j) {
        const float lb = isL ? lin_b[rb + j] : 0.f;
        float* dst = ws + (size_t)(b * 512 + rb + j) * 128;
        #pragma unroll
        for (int nf = 0; nf < 8; ++nf)
            dst[nf * 16 + lr] = acc[nf][j] + lb;
    }
}

// ---------------- K2: logits + softmax + PV + sigmoid (unchanged) ----------------
// grid (32 b, 8 it of 16 i-rows), 256 thr.
// R staged in LDS (4 chunks of 64 e-rows, double-buffered via 8 v4f regs);
// e-loop all-LDS. Phase-2 x transposed into the dead R buffers (XOR swizzle).
__global__ __launch_bounds__(256, 1) void k_attn(
    const float* __restrict__ x, const float* __restrict__ bias,
    const float* __restrict__ ws, float* __restrict__ out)
{
    __shared__ float Rs[2][8192];      // 64 KB; reused as xT after e-loop
    __shared__ float Lt[256 * 16];     // 16 KB: Lt[e*16+il]
    __shared__ float att[16 * 132];    // 8.4 KB
    __shared__ float as6[256], as4[256];

    const int t = threadIdx.x;
    const int b = blockIdx.x, it = blockIdx.y;
    const float* Pb = ws + (size_t)b * 65536;
    const float* Rsrc = Pb + 32768;    // R^T rows, contiguous 32 KB per chunk

    v4f rx[8];
#define RLOAD(n_) do { const float* s_ = Rsrc + (n_) * 8192 + t * 4;  \
    _Pragma("unroll") for (int q = 0; q < 8; ++q)                     \
      rx[q] = *(const v4f*)(s_ + q * 1024); } while (0)

    RLOAD(0);

    // stage L^T tile (coalesced) + a-vectors
    {
        const float* Ls = Pb + it * 16;
        #pragma unroll
        for (int q = 0; q < 4; ++q) {
            const int idx = t + q * 256;
            const int e = idx >> 2, il4 = (idx & 3) * 4;
            *(v4f*)&Lt[e * 16 + il4] = *(const v4f*)(Ls + e * 128 + il4);
        }
    }
    as6[t] = ws[WS_A6 + t];
    as4[t] = ws[WS_A4 + t];

    const int jp = t & 31, iq = t >> 5;
    const int j0 = jp * 4, il0 = iq * 2;

    float acc0[4] = {}, acc1[4] = {};      // sum 0.4a*|L+R| per jj, rows il0/il0+1
    float dr[4] = {};                      // sum 0.6a*R per jj
    float dl0 = 0.f, dl1 = 0.f;            // sum 0.6a*L per row

    #pragma unroll 1
    for (int n = 0; n < 4; ++n) {
        float* rs = &Rs[n & 1][0];
        {   // commit staged chunk n to LDS (linear, conflict-free sweep)
            float* d_ = rs + t * 4;
            #pragma unroll
            for (int q = 0; q < 8; ++q) *(v4f*)(d_ + q * 1024) = rx[q];
        }
        if (n < 3) RLOAD(n + 1);           // global latency covered by compute below
        __syncthreads();

        const int eg0 = n * 64;
        #pragma unroll
        for (int g = 0; g < 16; ++g) {
            const int e0 = g * 4, eg = eg0 + e0;
            v4f rv[4]; float2 lv[4];
            #pragma unroll
            for (int u = 0; u < 4; ++u) {
                rv[u] = *(const v4f*)&rs[(e0 + u) * 128 + j0];
                lv[u] = *(const float2*)&Lt[(eg + u) * 16 + il0];
            }
            const v4f a6v = *(const v4f*)&as6[eg];
            const v4f a4v = *(const v4f*)&as4[eg];
            #pragma unroll
            for (int u = 0; u < 4; ++u) {
                const float a6u = a6v[u], a4u = a4v[u];
                const float l0 = lv[u].x, l1 = lv[u].y;
                dl0 = fmaf(a6u, l0, dl0);
                dl1 = fmaf(a6u, l1, dl1);
                #pragma unroll
                for (int jj = 0; jj < 4; ++jj) {
                    const float r = rv[u][jj];
                    dr[jj]   = fmaf(a6u, r, dr[jj]);
                    acc0[jj] = fmaf(a4u, fabsf(l0 + r), acc0[jj]);
                    acc1[jj] = fmaf(a4u, fabsf(l1 + r), acc1[jj]);
                }
            }
        }
    }
    __syncthreads();                       // all waves done with Rs -> reuse as xT

    // stage xT[j][w ^ swz(j)] into the dead R buffers (64 KB exactly).
    float* xT = &Rs[0][0];
    {
        const float* xg = x + b * 16384;
        #pragma unroll
        for (int q = 0; q < 16; ++q) {
            const int idx = t + q * 256;
            const int w = idx >> 5, j4 = (idx & 31) * 4;
            const int s = ((j4 >> 2) & 15) << 1;
            const v4f xv = *(const v4f*)(xg + w * 128 + j4);
            xT[(j4 + 0) * 128 + (w ^ s)] = xv[0];
            xT[(j4 + 1) * 128 + (w ^ s)] = xv[1];
            xT[(j4 + 2) * 128 + (w ^ s)] = xv[2];
            xT[(j4 + 3) * 128 + (w ^ s)] = xv[3];
        }
    }

    // softmax over j (row lives in one 32-lane half-wave)
    const int i0r = it * 16 + il0;
    float ev0[4], ev1[4];
    {
        const v4f b0 = *(const v4f*)(bias + (i0r + 0) * 128 + j0);
        const v4f b1 = *(const v4f*)(bias + (i0r + 1) * 128 + j0);
        #pragma unroll
        for (int jj = 0; jj < 4; ++jj) {
            ev0[jj] = acc0[jj] + dl0 + dr[jj] + b0[jj];
            ev1[jj] = acc1[jj] + dl1 + dr[jj] + b1[jj];
        }
    }
#define SOFTMAX_ROW(EV, ROW) do {                                               \
    float m_ = fmaxf(fmaxf(EV[0], EV[1]), fmaxf(EV[2], EV[3]));                 \
    _Pragma("unroll") for (int d_ = 1; d_ <= 16; d_ <<= 1)                      \
        m_ = fmaxf(m_, __shfl_xor(m_, d_));                                     \
    float p0 = __expf(EV[0] - m_), p1 = __expf(EV[1] - m_);                     \
    float p2 = __expf(EV[2] - m_), p3 = __expf(EV[3] - m_);                     \
    float s_ = p0 + p1 + p2 + p3;                                               \
    _Pragma("unroll") for (int d_ = 1; d_ <= 16; d_ <<= 1)                      \
        s_ += __shfl_xor(s_, d_);                                               \
    const float inv_ = 1.f / s_;                                                \
    *(v4f*)&att[(ROW) * 132 + j0] =                                             \
        (v4f){p0 * inv_, p1 * inv_, p2 * inv_, p3 * inv_}; } while (0)

    SOFTMAX_ROW(ev0, il0 + 0);
    SOFTMAX_ROW(ev1, il0 + 1);
    __syncthreads();

    // phase 2: out[b][w][i] = sigmoid(sum_j att[i][j]*x[b][w][j]); lane 2w x 4i
    const int iq2 = t & 3, wp = t >> 2;
    const int i4 = iq2 * 4, w0 = wp * 2;
    float o[2][4] = {};
    #pragma unroll 4
    for (int jc = 0; jc < 32; ++jc) {
        const int wx = w0 ^ ((jc & 15) << 1);
        v4f av[4]; v2f xv[4];
        #pragma unroll
        for (int q = 0; q < 4; ++q)
            av[q] = *(const v4f*)&att[(i4 + q) * 132 + jc * 4];
        #pragma unroll
        for (int u = 0; u < 4; ++u)
            xv[u] = *(const v2f*)&xT[(jc * 4 + u) * 128 + wx];
        #pragma unroll
        for (int u = 0; u < 4; ++u)
            #pragma unroll
            for (int q = 0; q < 4; ++q) {
                o[0][q] = fmaf(xv[u].x, av[q][u], o[0][q]);
                o[1][q] = fmaf(xv[u].y, av[q][u], o[1][q]);
            }
    }
    #pragma unroll
    for (int w = 0; w < 2; ++w) {
        v4f r;
        r[0] = 1.f / (1.f + __expf(-o[w][0]));
        r[1] = 1.f / (1.f + __expf(-o[w][1]));
        r[2] = 1.f / (1.f + __expf(-o[w][2]));
        r[3] = 1.f / (1.f + __expf(-o[w][3]));
        *(v4f*)(out + (size_t)b * 16384 + (w0 + w) * 128 + it * 16 + i4) = r;
    }
}

extern "C" void kernel_launch(void* const* d_in, const int* in_sizes, int n_in,
                              void* d_out, int out_size, void* d_ws, size_t ws_size,
                              hipStream_t stream) {
    const float* x     = (const float*)d_in[0];
    const float* lin_w = (const float*)d_in[1];
    const float* lin_b = (const float*)d_in[2];
    const float* a     = (const float*)d_in[3];
    const float* bias  = (const float*)d_in[4];
    float* ws  = (float*)d_ws;
    float* out = (float*)d_out;

    k_linear<<<dim3(32, 8), 256, 0, stream>>>(x, lin_w, lin_b, a, ws);
    k_attn  <<<dim3(32, 8), 256, 0, stream>>>(x, bias, ws, out);
}